// Round 8
// baseline (383.812 us; speedup 1.0000x reference)
//
#include <hip/hip_runtime.h>
#include <stdint.h>

#define CC 22
#define START_I 20
#define STOP_I 21
#define BB 64
#define LL 512
#define DD 512
#define NEGV -100000.0f
#define NCH 32
#define CS 16
#define BPW 4   // batches per wave, software-interleaved independent chains

// ws layout
#define EMIT_FLOATS ((BB * LL + CS) * CC)                // + CS rows slack
#define BP_OFF (((EMIT_FLOATS * 4) + 255) & ~255)
#define BP_BYTES (BB * LL * CC)
#define META_OFF ((BP_OFF + BP_BYTES + 255) & ~255)
#define PV_OFF (META_OFF + 1024)                         // 64*32*22 floats

// ---------------- emissions GEMM: emit[row][c] = x[row]·W[c] + b[c] ----------------
// 2 classes per thread: thread = (row, cpair); 11 threads share one x row.
__global__ __launch_bounds__(256) void k_emit(const float* __restrict__ x,
                                              const float* __restrict__ W,
                                              const float* __restrict__ bias,
                                              float* __restrict__ emit) {
  __shared__ float Wl[CC * 516];  // row-major, stride 516 (16B aligned, bank-spread)
  int tid = threadIdx.x;
  for (int g = tid; g < CC * DD; g += 256) {
    int c = g >> 9;
    int d = g & (DD - 1);
    Wl[c * 516 + d] = W[g];
  }
  __syncthreads();
  int gtid = blockIdx.x * 256 + tid;  // 1408*256 = 360448 = 11 * 32768 exactly
  int c = gtid % 11;
  int row = gtid / 11;                // [0, 32768)
  float b0 = bias[c];
  float b1 = bias[c + 11];
  const float4* xr = (const float4*)(x + (size_t)row * DD);
  const float* w0 = Wl + c * 516;
  const float* w1 = Wl + (c + 11) * 516;
  float acc0 = 0.f, acc1 = 0.f;
#pragma unroll 4
  for (int i = 0; i < DD / 4; ++i) {
    float4 a = xr[i];
    float4 u = *(const float4*)(w0 + 4 * i);
    float4 v = *(const float4*)(w1 + 4 * i);
    acc0 += a.x * u.x + a.y * u.y + a.z * u.z + a.w * u.w;
    acc1 += a.x * v.x + a.y * v.y + a.z * v.z + a.w * v.w;
  }
  emit[(size_t)row * CC + c] = acc0 + b0;
  emit[(size_t)row * CC + c + 11] = acc1 + b1;
}

__device__ __forceinline__ float rlf(float v, int l) {
  return __int_as_float(__builtin_amdgcn_readlane(__float_as_int(v), l));
}

// One exact Viterbi step on state SREG (intrinsic readlanes: compiler owns all
// hazards). fmax is exactly associative -> value bit-identical to reference.
// ACT: wave-uniform (t < n_batch) select, matching reference's where(mask).
#define VS1(SREG, EV, ACT)                                        \
  {                                                               \
    float c0 = rlf(SREG, 0) + Tw[0], c1 = rlf(SREG, 1) + Tw[1];   \
    float c2 = rlf(SREG, 2) + Tw[2], c3 = rlf(SREG, 3) + Tw[3];   \
    float c4 = rlf(SREG, 4) + Tw[4], c5 = rlf(SREG, 5) + Tw[5];   \
    float c6 = rlf(SREG, 6) + Tw[6], c7 = rlf(SREG, 7) + Tw[7];   \
    float c8 = rlf(SREG, 8) + Tw[8], c9 = rlf(SREG, 9) + Tw[9];   \
    float c10 = rlf(SREG, 10) + Tw[10];                           \
    float c11 = rlf(SREG, 11) + Tw[11];                           \
    float c12 = rlf(SREG, 12) + Tw[12];                           \
    float c13 = rlf(SREG, 13) + Tw[13];                           \
    float c14 = rlf(SREG, 14) + Tw[14];                           \
    float c15 = rlf(SREG, 15) + Tw[15];                           \
    float c16 = rlf(SREG, 16) + Tw[16];                           \
    float c17 = rlf(SREG, 17) + Tw[17];                           \
    float c18 = rlf(SREG, 18) + Tw[18];                           \
    float c19 = rlf(SREG, 19) + Tw[19];                           \
    float c20 = rlf(SREG, 20) + Tw[20];                           \
    float c21 = rlf(SREG, 21) + Tw[21];                           \
    float m0 = fmaxf(fmaxf(c0, c1), c2);                          \
    float m1 = fmaxf(fmaxf(c3, c4), c5);                          \
    float m2 = fmaxf(fmaxf(c6, c7), c8);                          \
    float m3 = fmaxf(fmaxf(c9, c10), c11);                        \
    float m4 = fmaxf(fmaxf(c12, c13), c14);                       \
    float m5 = fmaxf(fmaxf(c15, c16), c17);                       \
    float m6 = fmaxf(fmaxf(c18, c19), c20);                       \
    float n0_ = fmaxf(fmaxf(m0, m1), m2);                         \
    float n1_ = fmaxf(fmaxf(m3, m4), m5);                         \
    float n2_ = fmaxf(m6, c21);                                   \
    float mx = fmaxf(fmaxf(n0_, n1_), n2_);                       \
    float ns = mx + (EV);                                         \
    SREG = (ACT) ? ns : SREG;                                     \
  }

// 4 independent batch chains per step q: B's readlanes issue while A's adds
// wait, etc. -> dependent-latency of each chain hides under the others.
#define STEPQ(Q)                                                  \
  {                                                               \
    const int tt = o * 8 + (Q);                                   \
    VS1(sA, eA[Q], tt < n0)                                       \
    VS1(sB, eB[Q], tt < n1)                                       \
    VS1(sC, eC[Q], tt < n2)                                       \
    VS1(sD, eD[Q], tt < n3)                                       \
  }

// ---------------- prefix pass: 4 batches per wave, lane = to-state ----------
__global__ __launch_bounds__(64, 1) void k_pfx(const float* __restrict__ emit,
                                               const float* __restrict__ mask,
                                               const float* __restrict__ trans,
                                               float* __restrict__ out_score,
                                               float* __restrict__ pv,
                                               int* __restrict__ meta) {
  const int b0 = blockIdx.x * BPW;
  const int lane = threadIdx.x;
  const int lc = lane < CC ? lane : CC - 1;

  float Tw[CC];  // trans[to=lane][frm=j], shared by all 4 batch chains
#pragma unroll
  for (int j = 0; j < CC; ++j) Tw[j] = trans[lc * CC + j];
  const float Tstop = trans[STOP_I * CC + lc];

  int n0 = 0, n1 = 0, n2 = 0, n3 = 0;
#pragma unroll
  for (int k = 0; k < 8; ++k) {
    n0 += __popcll(__ballot(mask[(size_t)(b0 + 0) * LL + k * 64 + lane] > 0.0f));
    n1 += __popcll(__ballot(mask[(size_t)(b0 + 1) * LL + k * 64 + lane] > 0.0f));
    n2 += __popcll(__ballot(mask[(size_t)(b0 + 2) * LL + k * 64 + lane] > 0.0f));
    n3 += __popcll(__ballot(mask[(size_t)(b0 + 3) * LL + k * 64 + lane] > 0.0f));
  }
  const int nmax = max(max(n0, n1), max(n2, n3));

  const float* e0 = emit + (size_t)(b0 + 0) * LL * CC;
  const float* e1 = emit + (size_t)(b0 + 1) * LL * CC;
  const float* e2 = emit + (size_t)(b0 + 2) * LL * CC;
  const float* e3 = emit + (size_t)(b0 + 3) * LL * CC;

  float sA = (lane == START_I) ? 0.0f : NEGV;
  float sB = sA, sC = sA, sD = sA;

  float eA[8], eB[8], eC[8], eD[8];
#pragma unroll
  for (int q = 0; q < 8; ++q) {
    eA[q] = e0[q * CC + lc];
    eB[q] = e1[q * CC + lc];
    eC[q] = e2[q * CC + lc];
    eD[q] = e3[q * CC + lc];
    asm volatile("" : "+v"(eA[q]), "+v"(eB[q]), "+v"(eC[q]), "+v"(eD[q]));
  }

  const int ototal = (nmax + 7) >> 3;
  for (int o = 0; o < ototal; ++o) {
    if (((o & 1) == 0) && lane < CC) {  // chunk checkpoint (state BEFORE 16c)
      const int ck = o >> 1;
      pv[((size_t)(b0 + 0) * NCH + ck) * CC + lane] = sA;
      pv[((size_t)(b0 + 1) * NCH + ck) * CC + lane] = sB;
      pv[((size_t)(b0 + 2) * NCH + ck) * CC + lane] = sC;
      pv[((size_t)(b0 + 3) * NCH + ck) * CC + lane] = sD;
    }
    float nA[8], nB[8], nC[8], nD[8];
#pragma unroll
    for (int q = 0; q < 8; ++q) {  // issue next-oct emission loads early
      nA[q] = e0[((o + 1) * 8 + q) * CC + lc];
      nB[q] = e1[((o + 1) * 8 + q) * CC + lc];
      nC[q] = e2[((o + 1) * 8 + q) * CC + lc];
      nD[q] = e3[((o + 1) * 8 + q) * CC + lc];
    }
    STEPQ(0) STEPQ(1) STEPQ(2) STEPQ(3)
    STEPQ(4) STEPQ(5) STEPQ(6) STEPQ(7)
#pragma unroll
    for (int q = 0; q < 8; ++q) {
      asm volatile("" : "+v"(nA[q]), "+v"(nB[q]), "+v"(nC[q]), "+v"(nD[q]));
      eA[q] = nA[q]; eB[q] = nB[q]; eC[q] = nC[q]; eD[q] = nD[q];
    }
  }

  const float fA = sA + Tstop, fB = sB + Tstop, fC = sC + Tstop, fD = sD + Tstop;
  if (lane < CC) {
    out_score[(size_t)(b0 + 0) * CC + lane] = fA;
    out_score[(size_t)(b0 + 1) * CC + lane] = fB;
    out_score[(size_t)(b0 + 2) * CC + lane] = fC;
    out_score[(size_t)(b0 + 3) * CC + lane] = fD;
  }

  // best tag per batch: uniform readlane sweep (strict > = first-index ties)
#define BEST(FIN, BT)                       \
  {                                         \
    float bv = -3.0e38f;                    \
    BT = 0;                                 \
    _Pragma("unroll") for (int k = 0; k < CC; ++k) { \
      float v = rlf(FIN, k);                \
      bool g = v > bv;                      \
      bv = g ? v : bv;                      \
      BT = g ? k : BT;                      \
    }                                       \
  }
  int btA, btB, btC, btD;
  BEST(fA, btA) BEST(fB, btB) BEST(fC, btC) BEST(fD, btD)
#undef BEST
  if (lane == 0) {
    meta[b0 + 0] = n0; meta[BB + b0 + 0] = btA;
    meta[b0 + 1] = n1; meta[BB + b0 + 1] = btB;
    meta[b0 + 2] = n2; meta[BB + b0 + 2] = btC;
    meta[b0 + 3] = n3; meta[BB + b0 + 3] = btD;
  }
}

// ---------------- parallel replay: backpointers from exact checkpoints ----------------
__global__ __launch_bounds__(64) void k_rep(const float* __restrict__ emit,
                                            const float* __restrict__ trans,
                                            const float* __restrict__ pv,
                                            const int* __restrict__ meta,
                                            unsigned char* __restrict__ bp) {
  const int c = blockIdx.x, b = blockIdx.y;
  const int lane = threadIdx.x;
  const int n = meta[b];
  const int t0 = c * CS;
  if (t0 >= n) return;
  const int lc = lane < CC ? lane : CC - 1;
  float Trow[CC];
#pragma unroll
  for (int j = 0; j < CC; ++j) Trow[j] = trans[lc * CC + j];
  float st = pv[((size_t)b * NCH + c) * CC + lc];
  const float* eb = emit + (size_t)b * LL * CC;
  float ev[CS];
#pragma unroll
  for (int q = 0; q < CS; ++q) {
    ev[q] = eb[(t0 + q) * CC + lc];
    asm volatile("" : "+v"(ev[q]));
  }
  unsigned char* bpb = bp + (size_t)b * LL * CC;
  const int m = (n - t0) < CS ? (n - t0) : CS;
#pragma unroll
  for (int q = 0; q < CS; ++q) {
    if (q < m) {
      float cand[CC];
#pragma unroll
      for (int j = 0; j < CC; ++j) cand[j] = rlf(st, j) + Trow[j];
      float m0 = fmaxf(fmaxf(cand[0], cand[1]), cand[2]);
      float m1 = fmaxf(fmaxf(cand[3], cand[4]), cand[5]);
      float m2 = fmaxf(fmaxf(cand[6], cand[7]), cand[8]);
      float m3 = fmaxf(fmaxf(cand[9], cand[10]), cand[11]);
      float m4 = fmaxf(fmaxf(cand[12], cand[13]), cand[14]);
      float m5 = fmaxf(fmaxf(cand[15], cand[16]), cand[17]);
      float m6 = fmaxf(fmaxf(cand[18], cand[19]), cand[20]);
      float n0 = fmaxf(fmaxf(m0, m1), m2);
      float n1 = fmaxf(fmaxf(m3, m4), m5);
      float n2 = fmaxf(m6, cand[21]);
      float mx = fmaxf(fmaxf(n0, n1), n2);
      // first-index argmax over frm (matches jnp.argmax tie-break)
      unsigned u = 0;
#pragma unroll
      for (int j = 0; j < CC; ++j) u |= (cand[j] == mx) ? (1u << j) : 0u;
      int bpi = __builtin_ctz(u);
      if (lane < CC) bpb[(t0 + q) * CC + lane] = (unsigned char)bpi;
      st = mx + ev[q];
    }
  }
}

// ---------------- backtrace: chunk-composed backpointer maps ----------------
__global__ __launch_bounds__(64) void k_back(const unsigned char* __restrict__ bp,
                                             const int* __restrict__ meta,
                                             float* __restrict__ out_path) {
  __shared__ __align__(16) unsigned char bps[LL * CC];  // 11264 B
  __shared__ unsigned char gs[64 * CC];                 // per-chunk composed maps
  const int b = blockIdx.x, lane = threadIdx.x;
  const int n = meta[b];
  const int bt = meta[BB + b];
  const uint32_t* src = (const uint32_t*)(bp + (size_t)b * LL * CC);
  uint32_t* dst = (uint32_t*)bps;
  for (int i = lane; i < (LL * CC) / 4; i += 64) dst[i] = src[i];
  __syncthreads();
  // lane k composes the 8-step map of chunk k (inactive steps = identity)
  const int k = lane;
  for (int c = 0; c < CC; ++c) {
    int tag = c;
#pragma unroll
    for (int j = 7; j >= 0; --j) {
      int t = 8 * k + j;
      int nv = bps[t * CC + tag];
      tag = (t < n) ? nv : tag;
    }
    gs[k * CC + c] = (unsigned char)tag;
  }
  __syncthreads();
  // 64-step dependent chain over chunk maps (broadcast LDS reads)
  int tag = bt, entry = bt;
  for (int kk = 63; kk >= 0; --kk) {
    if (lane == kk) entry = tag;
    tag = gs[kk * CC + tag];
  }
  // parallel replay within each chunk
  tag = entry;
  float* op = out_path + (size_t)b * LL;
#pragma unroll
  for (int j = 7; j >= 0; --j) {
    int t = 8 * k + j;
    bool act = t < n;
    op[t] = act ? (float)tag : 0.0f;
    int nv = bps[t * CC + tag];
    tag = act ? nv : tag;
  }
}

extern "C" void kernel_launch(void* const* d_in, const int* in_sizes, int n_in,
                              void* d_out, int out_size, void* d_ws, size_t ws_size,
                              hipStream_t stream) {
  const float* x = (const float*)d_in[0];
  const float* mask = (const float*)d_in[1];
  const float* W = (const float*)d_in[2];
  const float* bias = (const float*)d_in[3];
  const float* trans = (const float*)d_in[4];
  float* out_score = (float*)d_out;                 // [B, C] f32
  float* out_path = (float*)d_out + BB * CC;        // [B, L] written as f32 values
  char* ws = (char*)d_ws;
  float* emit = (float*)ws;
  unsigned char* bp = (unsigned char*)(ws + BP_OFF);
  int* meta = (int*)(ws + META_OFF);
  float* pvp = (float*)(ws + PV_OFF);

  k_emit<<<dim3(1408), dim3(256), 0, stream>>>(x, W, bias, emit);
  k_pfx<<<dim3(BB / BPW), dim3(64), 0, stream>>>(emit, mask, trans, out_score, pvp, meta);
  k_rep<<<dim3(NCH, BB), dim3(64), 0, stream>>>(emit, trans, pvp, meta, bp);
  k_back<<<dim3(BB), dim3(64), 0, stream>>>(bp, meta, out_path);
}

// Round 9
// 91.716 us; speedup vs baseline: 4.1848x; 4.1848x over previous
//
#include <hip/hip_runtime.h>
#include <stdint.h>
#include <math.h>

#define CC 22
#define START_I 20
#define STOP_I 21
#define BB 64
#define LL 512
#define DD 512
#define NEGV -100000.0f
#define NCH 32
#define CS 16

// ws layout
#define EMIT_FLOATS ((BB * LL + CS) * CC)                // + CS rows slack
#define BP_OFF (((EMIT_FLOATS * 4) + 255) & ~255)
#define BP_BYTES (BB * LL * CC)
#define META_OFF ((BP_OFF + BP_BYTES + 255) & ~255)
#define PV_OFF (META_OFF + 1024)                         // 64*32*22 floats = 180224 B
#define PHI_OFF (PV_OFF + BB * NCH * CC * 4)             // 64*32*22*22 floats = 3.96 MB

// ---------------- emissions GEMM: emit[row][c] = x[row]·W[c] + b[c] ----------------
__global__ __launch_bounds__(256) void k_emit(const float* __restrict__ x,
                                              const float* __restrict__ W,
                                              const float* __restrict__ bias,
                                              float* __restrict__ emit) {
  __shared__ float Wl[CC * 516];  // row-major, stride 516 (16B aligned, bank-spread)
  int tid = threadIdx.x;
  for (int g = tid; g < CC * DD; g += 256) {
    int c = g >> 9;
    int d = g & (DD - 1);
    Wl[c * 516 + d] = W[g];
  }
  __syncthreads();
  int gtid = blockIdx.x * 256 + tid;  // 1408*256 = 360448 = 11 * 32768 exactly
  int c = gtid % 11;
  int row = gtid / 11;                // [0, 32768)
  float b0 = bias[c];
  float b1 = bias[c + 11];
  const float4* xr = (const float4*)(x + (size_t)row * DD);
  const float* w0 = Wl + c * 516;
  const float* w1 = Wl + (c + 11) * 516;
  float acc0 = 0.f, acc1 = 0.f;
#pragma unroll 4
  for (int i = 0; i < DD / 4; ++i) {
    float4 a = xr[i];
    float4 u = *(const float4*)(w0 + 4 * i);
    float4 v = *(const float4*)(w1 + 4 * i);
    acc0 += a.x * u.x + a.y * u.y + a.z * u.z + a.w * u.w;
    acc1 += a.x * v.x + a.y * v.y + a.z * v.z + a.w * v.w;
  }
  emit[(size_t)row * CC + c] = acc0 + b0;
  emit[(size_t)row * CC + c + 11] = acc1 + b1;
}

__device__ __forceinline__ float rlf(float v, int l) {
  return __int_as_float(__builtin_amdgcn_readlane(__float_as_int(v), l));
}

// ---------------- segment transfer matrices (parallel-in-time Viterbi) ----------
// Block (seg, b): Phi[to][frm0] = best score from state frm0 at t0 to state `to`
// after the segment's active steps (inactive steps = identity by construction).
// 242 threads own 2 cells each; Phi double-buffered in LDS (stride 23: no
// bank conflicts); max is exactly associative -> only add-grouping differs
// from the reference (ULP-level, far under threshold).
__global__ __launch_bounds__(256) void k_seg(const float* __restrict__ emit,
                                             const float* __restrict__ mask,
                                             const float* __restrict__ trans,
                                             float* __restrict__ phi) {
  __shared__ float Ph[2][CC][23];
  __shared__ float els[CS * CC];
  const int seg = blockIdx.x, b = blockIdx.y;
  const int tid = threadIdx.x;
  const int lane = tid & 63;
  int n = 0;  // each wave computes redundantly (no sync needed)
#pragma unroll
  for (int k = 0; k < 8; ++k)
    n += __popcll(__ballot(mask[(size_t)b * LL + k * 64 + lane] > 0.0f));
  const int t0 = seg * CS;
  if (tid < CS * CC) els[tid] = emit[((size_t)b * LL + t0) * CC + tid];
  const bool own = tid < 242;
  const int to2 = own ? tid / CC : 0;   // 0..10
  const int frm0 = own ? tid % CC : 0;  // 0..21
  float T0[CC], T1[CC];
  if (own) {
#pragma unroll
    for (int f = 0; f < CC; ++f) {
      T0[f] = trans[to2 * CC + f];
      T1[f] = trans[(to2 + 11) * CC + f];
    }
    Ph[0][to2][frm0] = (to2 == frm0) ? 0.0f : -INFINITY;
    Ph[0][to2 + 11][frm0] = (to2 + 11 == frm0) ? 0.0f : -INFINITY;
  }
  __syncthreads();
  int steps = n - t0;
  steps = steps < 0 ? 0 : (steps > CS ? CS : steps);
  int c = 0;
  for (int q = 0; q < steps; ++q) {  // block-uniform trip count
    if (own) {
      float a0 = -INFINITY, a1 = -INFINITY;
#pragma unroll
      for (int f = 0; f < CC; ++f) {
        float v = Ph[c][f][frm0];
        a0 = fmaxf(a0, v + T0[f]);
        a1 = fmaxf(a1, v + T1[f]);
      }
      Ph[c ^ 1][to2][frm0] = a0 + els[q * CC + to2];
      Ph[c ^ 1][to2 + 11][frm0] = a1 + els[q * CC + to2 + 11];
    }
    __syncthreads();
    c ^= 1;
  }
  if (own) {
    float* pb = phi + ((size_t)b * NCH + seg) * CC * CC;
    pb[to2 * CC + frm0] = Ph[c][to2][frm0];
    pb[(to2 + 11) * CC + frm0] = Ph[c][to2 + 11][frm0];
  }
}

// ---------------- compose: 32 matrix-vector max-plus steps per batch ----------
__global__ __launch_bounds__(64) void k_cmp(const float* __restrict__ phi,
                                            const float* __restrict__ mask,
                                            const float* __restrict__ trans,
                                            float* __restrict__ out_score,
                                            float* __restrict__ pv,
                                            int* __restrict__ meta) {
  const int b = blockIdx.x;
  const int lane = threadIdx.x;
  const int lc = lane < CC ? lane : CC - 1;
  const float Tstop = trans[STOP_I * CC + lc];
  int n = 0;
#pragma unroll
  for (int k = 0; k < 8; ++k)
    n += __popcll(__ballot(mask[(size_t)b * LL + k * 64 + lane] > 0.0f));

  float st = (lane == START_I) ? 0.0f : NEGV;
  const float* pb = phi + (size_t)b * NCH * CC * CC;
  float row[CC], nrow[CC];
#pragma unroll
  for (int f = 0; f < CC; ++f) row[f] = pb[lc * CC + f];
  for (int s = 0; s < NCH; ++s) {
    if (lane < CC) pv[((size_t)b * NCH + s) * CC + lane] = st;
    if (s + 1 < NCH) {
#pragma unroll
      for (int f = 0; f < CC; ++f) nrow[f] = pb[((s + 1) * CC + lc) * CC + f];
    }
    float a = -INFINITY;
#pragma unroll
    for (int f = 0; f < CC; ++f) a = fmaxf(a, row[f] + rlf(st, f));
    st = a;  // identity segments preserve st exactly
#pragma unroll
    for (int f = 0; f < CC; ++f) row[f] = nrow[f];
  }

  float fin = st + Tstop;
  if (lane < CC) out_score[b * CC + lane] = fin;
  float bv = -3.0e38f;
  int bt = 0;
#pragma unroll
  for (int k = 0; k < CC; ++k) {
    float v = rlf(fin, k);
    bool g = v > bv;
    bv = g ? v : bv;
    bt = g ? k : bt;
  }
  if (lane == 0) { meta[b] = n; meta[BB + b] = bt; }
}

// ---------------- parallel replay: backpointers from checkpoints ----------------
__global__ __launch_bounds__(64) void k_rep(const float* __restrict__ emit,
                                            const float* __restrict__ trans,
                                            const float* __restrict__ pv,
                                            const int* __restrict__ meta,
                                            unsigned char* __restrict__ bp) {
  const int c = blockIdx.x, b = blockIdx.y;
  const int lane = threadIdx.x;
  const int n = meta[b];
  const int t0 = c * CS;
  if (t0 >= n) return;
  const int lc = lane < CC ? lane : CC - 1;
  float Trow[CC];
#pragma unroll
  for (int j = 0; j < CC; ++j) Trow[j] = trans[lc * CC + j];
  float st = pv[((size_t)b * NCH + c) * CC + lc];
  const float* eb = emit + (size_t)b * LL * CC;
  float ev[CS];
#pragma unroll
  for (int q = 0; q < CS; ++q) {
    ev[q] = eb[(t0 + q) * CC + lc];
    asm volatile("" : "+v"(ev[q]));
  }
  unsigned char* bpb = bp + (size_t)b * LL * CC;
  const int m = (n - t0) < CS ? (n - t0) : CS;
#pragma unroll
  for (int q = 0; q < CS; ++q) {
    if (q < m) {
      float cand[CC];
#pragma unroll
      for (int j = 0; j < CC; ++j) cand[j] = rlf(st, j) + Trow[j];
      float m0 = fmaxf(fmaxf(cand[0], cand[1]), cand[2]);
      float m1 = fmaxf(fmaxf(cand[3], cand[4]), cand[5]);
      float m2 = fmaxf(fmaxf(cand[6], cand[7]), cand[8]);
      float m3 = fmaxf(fmaxf(cand[9], cand[10]), cand[11]);
      float m4 = fmaxf(fmaxf(cand[12], cand[13]), cand[14]);
      float m5 = fmaxf(fmaxf(cand[15], cand[16]), cand[17]);
      float m6 = fmaxf(fmaxf(cand[18], cand[19]), cand[20]);
      float n0 = fmaxf(fmaxf(m0, m1), m2);
      float n1 = fmaxf(fmaxf(m3, m4), m5);
      float n2 = fmaxf(m6, cand[21]);
      float mx = fmaxf(fmaxf(n0, n1), n2);
      unsigned u = 0;
#pragma unroll
      for (int j = 0; j < CC; ++j) u |= (cand[j] == mx) ? (1u << j) : 0u;
      int bpi = __builtin_ctz(u);
      if (lane < CC) bpb[(t0 + q) * CC + lane] = (unsigned char)bpi;
      st = mx + ev[q];
    }
  }
}

// ---------------- backtrace: chunk-composed backpointer maps ----------------
__global__ __launch_bounds__(64) void k_back(const unsigned char* __restrict__ bp,
                                             const int* __restrict__ meta,
                                             float* __restrict__ out_path) {
  __shared__ __align__(16) unsigned char bps[LL * CC];  // 11264 B
  __shared__ unsigned char gs[64 * CC];
  const int b = blockIdx.x, lane = threadIdx.x;
  const int n = meta[b];
  const int bt = meta[BB + b];
  const uint32_t* src = (const uint32_t*)(bp + (size_t)b * LL * CC);
  uint32_t* dst = (uint32_t*)bps;
  for (int i = lane; i < (LL * CC) / 4; i += 64) dst[i] = src[i];
  __syncthreads();
  const int k = lane;
  for (int c = 0; c < CC; ++c) {
    int tag = c;
#pragma unroll
    for (int j = 7; j >= 0; --j) {
      int t = 8 * k + j;
      int nv = bps[t * CC + tag];
      tag = (t < n) ? nv : tag;
    }
    gs[k * CC + c] = (unsigned char)tag;
  }
  __syncthreads();
  int tag = bt, entry = bt;
  for (int kk = 63; kk >= 0; --kk) {
    if (lane == kk) entry = tag;
    tag = gs[kk * CC + tag];
  }
  tag = entry;
  float* op = out_path + (size_t)b * LL;
#pragma unroll
  for (int j = 7; j >= 0; --j) {
    int t = 8 * k + j;
    bool act = t < n;
    op[t] = act ? (float)tag : 0.0f;
    int nv = bps[t * CC + tag];
    tag = act ? nv : tag;
  }
}

extern "C" void kernel_launch(void* const* d_in, const int* in_sizes, int n_in,
                              void* d_out, int out_size, void* d_ws, size_t ws_size,
                              hipStream_t stream) {
  const float* x = (const float*)d_in[0];
  const float* mask = (const float*)d_in[1];
  const float* W = (const float*)d_in[2];
  const float* bias = (const float*)d_in[3];
  const float* trans = (const float*)d_in[4];
  float* out_score = (float*)d_out;                 // [B, C] f32
  float* out_path = (float*)d_out + BB * CC;        // [B, L] as f32 values
  char* ws = (char*)d_ws;
  float* emit = (float*)ws;
  unsigned char* bp = (unsigned char*)(ws + BP_OFF);
  int* meta = (int*)(ws + META_OFF);
  float* pvp = (float*)(ws + PV_OFF);
  float* phi = (float*)(ws + PHI_OFF);

  k_emit<<<dim3(1408), dim3(256), 0, stream>>>(x, W, bias, emit);
  k_seg<<<dim3(NCH, BB), dim3(256), 0, stream>>>(emit, mask, trans, phi);
  k_cmp<<<dim3(BB), dim3(64), 0, stream>>>(phi, mask, trans, out_score, pvp, meta);
  k_rep<<<dim3(NCH, BB), dim3(64), 0, stream>>>(emit, trans, pvp, meta, bp);
  k_back<<<dim3(BB), dim3(64), 0, stream>>>(bp, meta, out_path);
}